// Round 7
// baseline (232.600 us; speedup 1.0000x reference)
//
#include <hip/hip_runtime.h>
#include <cstdint>
#include <cstddef>

typedef unsigned short u16;
typedef __attribute__((ext_vector_type(8))) short short8;
typedef __attribute__((ext_vector_type(4))) float f32x4;
typedef __attribute__((ext_vector_type(4))) unsigned int u32x4;

#define GLOBAL_AS(p) ((const __attribute__((address_space(1))) void*)(p))
#define LDS_AS(p)    ((__attribute__((address_space(3))) void*)(p))
typedef __attribute__((address_space(3))) const void* lds_cp;

__device__ __forceinline__ float bf2f(u16 u){
  union { uint32_t u; float f; } c; c.u = ((uint32_t)u) << 16; return c.f;
}
__device__ __forceinline__ float lo16(uint32_t u){
  union { uint32_t u; float f; } c; c.u = u << 16; return c.f;
}
__device__ __forceinline__ float hi16(uint32_t u){
  union { uint32_t u; float f; } c; c.u = u & 0xffff0000u; return c.f;
}
__device__ __forceinline__ u16 f2bf(float f){
  union { float f; uint32_t u; } c; c.f = f;
  uint32_t r = c.u + 0x7fffu + ((c.u >> 16) & 1u);
  return (u16)(r >> 16);
}

// ---------------- LayerNorm + cast to bf16 (one block per 768-elem row) ----
__global__ __launch_bounds__(256) void ln_cast(const float* __restrict__ x,
    const float* __restrict__ g, const float* __restrict__ bta,
    u16* __restrict__ y)
{
  const size_t row = blockIdx.x;
  const float* xr = x + row * 768;
  const int t = threadIdx.x;
  float v0 = xr[t], v1 = xr[t+256], v2 = xr[t+512];
  float s = v0+v1+v2;
  float q = v0*v0 + v1*v1 + v2*v2;
  #pragma unroll
  for (int o=1;o<64;o<<=1){ s += __shfl_xor(s,o); q += __shfl_xor(q,o); }
  __shared__ float rs_[4], rq_[4];
  if ((t & 63) == 0){ rs_[t>>6] = s; rq_[t>>6] = q; }
  __syncthreads();
  s = rs_[0]+rs_[1]+rs_[2]+rs_[3];
  q = rq_[0]+rq_[1]+rq_[2]+rq_[3];
  const float m = s * (1.f/768.f);
  const float var = q * (1.f/768.f) - m*m;
  const float rstd = rsqrtf(var + 1e-6f);
  u16* yr = y + row * 768;
  yr[t]     = f2bf((v0-m)*rstd*g[t]     + bta[t]);
  yr[t+256] = f2bf((v1-m)*rstd*g[t+256] + bta[t+256]);
  yr[t+512] = f2bf((v2-m)*rstd*g[t+512] + bta[t+512]);
}

// ---------------- transpose+cast: out[n][k] = bf16(in[k*ld + n]), k<768 ----
__global__ __launch_bounds__(256) void tcast(const float* __restrict__ in,
    int ld, int ncnt, u16* __restrict__ out)
{
  __shared__ float tile[32][33];
  const int tx = threadIdx.x & 31, ty = threadIdx.x >> 5;
  const int n0 = blockIdx.x * 32, k0 = blockIdx.y * 32;
  #pragma unroll
  for (int i=0;i<4;i++){
    int k = k0 + ty + 8*i, n = n0 + tx;
    tile[ty+8*i][tx] = (n < ncnt) ? in[(size_t)k*ld + n] : 0.f;
  }
  __syncthreads();
  #pragma unroll
  for (int i=0;i<4;i++){
    int n = n0 + ty + 8*i, k = k0 + tx;
    if (n < ncnt) out[(size_t)n*768 + k] = f2bf(tile[tx][ty+8*i]);
  }
}

__global__ void pack_bsa(const float* __restrict__ bs, const float* __restrict__ ba,
                         float* __restrict__ bsa)
{
  int t = threadIdx.x;
  bsa[t] = (t < 144) ? bs[t] : ((t < 216) ? ba[t-144] : 0.f);
}

// ================== 8-phase pipelined 256x256 MFMA GEMM (v3) ===============
// v3 = v2 with all K-loop ds_reads as inline asm (no memory clobber) so the
// compiler's waitcnt pass cannot insert alias-forced vmcnt(0) drains before
// LDS reads (global_load_lds leaves vmcnt pending; the pass can't prove the
// ds_read targets the other buffer). Waits are provided manually:
// lgkmcnt(0)+sched_barrier(0) before each MFMA burst covers all reads issued
// in the previous phase (rule #18). Stage ledger identical to R4/R5 (proven):
//   p0: A(b)x2->buf1 | p1: B0(a+2)->buf0 | p2: B1(a+2) | p3: VM4
//   p4: A0(a+2)->buf0 | p5: A1(a+2) | p6: B0(b+2)->buf1 | p7: B1(b+2), VM4
// vmcnt(4) leaves 2 half-tiles in flight; never 0 in loop.
__global__ __launch_bounds__(512, 2) void gemm8(
    const u16* __restrict__ A, const u16* __restrict__ Bt,
    const float* __restrict__ bias,
    u16* __restrict__ Cout, int M, int N, int K, int nbx)
{
  __shared__ u16 lds[2][2][256*64];
  const int nwg = gridDim.x;                       // multiple of 8
  const int bid = blockIdx.x;
  const int swz = (bid & 7) * (nwg >> 3) + (bid >> 3);
  const int bx = swz % nbx, by = swz / nbx;
  const int m0 = by*256, n0 = bx*256;
  const int t = threadIdx.x, w = t >> 6, lane = t & 63;
  const int wm = w >> 2, wn = w & 3;
  const int NT = K >> 6;
  const int lr = lane & 15, r7 = lane & 7;

  // staging: half-tile (128x64) = 2 gload_lds(16B)/thread; lane l -> row
  // (w*8 + l>>3)+{0,64}, chunk l&7; source chunk pre-swizzled (lane-linear
  // LDS write): c_src = (l&7) ^ ((l>>3)&7).
  const int stRow  = (w << 3) + (lane >> 3);
  const int stColU = (((lane & 7) ^ ((lane >> 3) & 7)) << 3);

  f32x4 acc[8][4];
  #pragma unroll
  for (int j=0;j<8;j++)
    #pragma unroll
    for (int ni=0;ni<4;ni++)
      acc[j][ni] = (f32x4){0.f,0.f,0.f,0.f};

  #define STAGE(op, half, kt, buf, G, gbase)                                   \
    { const u16* gsrc_ = (G) + (size_t)((gbase) + (half)*128 + stRow)*K        \
                              + (kt)*64 + stColU;                              \
      u16* l_ = &lds[buf][op][((half)*128 + (w<<3))*64];                       \
      __builtin_amdgcn_global_load_lds(GLOBAL_AS(gsrc_), LDS_AS(l_), 16,0,0);  \
      __builtin_amdgcn_global_load_lds(GLOBAL_AS(gsrc_ + (size_t)64*K),        \
                                       LDS_AS(l_ + 64*64), 16,0,0); }

  // read-side swizzle: chunk c at row R lives in slot c ^ (R&7)
  const int slot0 = ((0 + (lane>>4)) ^ r7) * 8;     // kk=0
  const int slot1 = ((4 + (lane>>4)) ^ r7) * 8;     // kk=1

  // prologue: A(0),B(0)->buf0 (8 loads); B(1)->buf1 (4). vmcnt(4) -> A0,B0 in.
  STAGE(0,0,0,0, A,  m0); STAGE(0,1,0,0, A,  m0);
  STAGE(1,0,0,0, Bt, n0); STAGE(1,1,0,0, Bt, n0);
  STAGE(1,0,1,1, Bt, n0); STAGE(1,1,1,1, Bt, n0);
  asm volatile("s_waitcnt vmcnt(4)" ::: "memory");
  __builtin_amdgcn_s_barrier();

  const u16* lA0 = &lds[0][0][(wm*128 + lr)*64];
  const u16* lB0 = &lds[0][1][(wn*64  + lr)*64];
  const u16* lA1 = &lds[1][0][(wm*128 + lr)*64];
  const u16* lB1 = &lds[1][1][(wn*64  + lr)*64];

  short8 bf_[4][2], aX[4], aY[4];

  // inline-asm ds_read_b128: invisible to the compiler's waitcnt pass ->
  // no alias-forced vmcnt(0); we own the lgkm waits.
  #define DSR(dst_, p_)                                                        \
    asm volatile("ds_read_b128 %0, %1" : "=v"(dst_) : "v"((lds_cp)(p_)))

  #define READ_A(dst_, lA_, jp_)                                               \
    DSR(dst_[0], (lA_) + ((jp_)*32     )*64 + slot0);                          \
    DSR(dst_[1], (lA_) + ((jp_)*32     )*64 + slot1);                          \
    DSR(dst_[2], (lA_) + ((jp_)*32 + 16)*64 + slot0);                          \
    DSR(dst_[3], (lA_) + ((jp_)*32 + 16)*64 + slot1);

  #define READ_B(lB_)                                                          \
    DSR(bf_[0][0], (lB_) +  0*64 + slot0);  DSR(bf_[0][1], (lB_) +  0*64 + slot1); \
    DSR(bf_[1][0], (lB_) + 16*64 + slot0);  DSR(bf_[1][1], (lB_) + 16*64 + slot1); \
    DSR(bf_[2][0], (lB_) + 32*64 + slot0);  DSR(bf_[2][1], (lB_) + 32*64 + slot1); \
    DSR(bf_[3][0], (lB_) + 48*64 + slot0);  DSR(bf_[3][1], (lB_) + 48*64 + slot1);

  #define MFMA16(aR_, jp_)                                                     \
    _Pragma("unroll")                                                          \
    for (int ni=0; ni<4; ++ni) {                                               \
      acc[2*(jp_)  ][ni] = __builtin_amdgcn_mfma_f32_16x16x32_bf16(aR_[0], bf_[ni][0], acc[2*(jp_)  ][ni], 0,0,0); \
      acc[2*(jp_)  ][ni] = __builtin_amdgcn_mfma_f32_16x16x32_bf16(aR_[1], bf_[ni][1], acc[2*(jp_)  ][ni], 0,0,0); \
      acc[2*(jp_)+1][ni] = __builtin_amdgcn_mfma_f32_16x16x32_bf16(aR_[2], bf_[ni][0], acc[2*(jp_)+1][ni], 0,0,0); \
      acc[2*(jp_)+1][ni] = __builtin_amdgcn_mfma_f32_16x16x32_bf16(aR_[3], bf_[ni][1], acc[2*(jp_)+1][ni], 0,0,0); \
    }

  #define LGKM0 do { asm volatile("s_waitcnt lgkmcnt(0)" ::: "memory");        \
                     __builtin_amdgcn_sched_barrier(0); } while(0)
  #define BAR   __builtin_amdgcn_s_barrier()
  #define VM4   asm volatile("s_waitcnt vmcnt(4)" ::: "memory")
  #define SETP1 __builtin_amdgcn_s_setprio(1)
  #define SETP0 __builtin_amdgcn_s_setprio(0)

  const int NITER = NT >> 1;
  for (int i = 0; i < NITER; ++i) {
    const int bt = 2*i + 1;
    const int a2 = (2*i+2 < NT) ? 2*i+2 : NT-1;
    const int b2 = (bt +2 < NT) ? bt +2 : NT-1;

    // ---- tile a (buf0) ----
    READ_B(lB0); READ_A(aX, lA0, 0);                 // p0 cold: 12 reads
    STAGE(0,0,bt,1, A, m0); STAGE(0,1,bt,1, A, m0);
    LGKM0;
    READ_A(aY, lA0, 1);                              // prefetch q1 under MFMA
    SETP1; MFMA16(aX, 0); SETP0;
    BAR;

    STAGE(1,0,a2,0, Bt, n0);                         // p1
    LGKM0;
    READ_A(aX, lA0, 2);
    SETP1; MFMA16(aY, 1); SETP0;
    BAR;

    STAGE(1,1,a2,0, Bt, n0);                         // p2
    LGKM0;
    READ_A(aY, lA0, 3);
    SETP1; MFMA16(aX, 2); SETP0;
    BAR;

    LGKM0;                                           // p3
    SETP1; MFMA16(aY, 3); SETP0;
    VM4; BAR;                                        // buf1 (tile b) ready

    // ---- tile b (buf1) ----
    READ_B(lB1); READ_A(aX, lA1, 0);                 // p4 cold
    STAGE(0,0,a2,0, A, m0);
    LGKM0;
    READ_A(aY, lA1, 1);
    SETP1; MFMA16(aX, 0); SETP0;
    BAR;

    STAGE(0,1,a2,0, A, m0);                          // p5
    LGKM0;
    READ_A(aX, lA1, 2);
    SETP1; MFMA16(aY, 1); SETP0;
    BAR;

    STAGE(1,0,b2,1, Bt, n0);                         // p6
    LGKM0;
    READ_A(aY, lA1, 3);
    SETP1; MFMA16(aX, 2); SETP0;
    BAR;

    STAGE(1,1,b2,1, Bt, n0);                         // p7
    LGKM0;
    SETP1; MFMA16(aY, 3); SETP0;
    VM4; BAR;                                        // buf0 (tile a+2) ready
  }
  #undef STAGE
  #undef READ_A
  #undef READ_B
  #undef MFMA16
  #undef LGKM0
  #undef VM4
  #undef DSR

  // ---- epilogue: restage C through LDS for coalesced stores ----
  asm volatile("s_waitcnt vmcnt(0)" ::: "memory");   // drain tail stages
  BAR;                                               // LDS now dead -> reuse
  u16* lsc = (u16*)lds;                              // 256x256 u16 = 128 KiB
  #pragma unroll
  for (int ni=0;ni<4;ni++){
    const int col = wn*64 + ni*16 + lr;
    const float bc = bias[n0 + col];
    #pragma unroll
    for (int j=0;j<8;j++){
      const int row0 = wm*128 + j*16 + (lane>>4)*4;
      #pragma unroll
      for (int r=0;r<4;r++)
        lsc[(row0+r)*256 + col] = f2bf(acc[j][ni][r] + bc);
    }
  }
  BAR;
  #pragma unroll
  for (int it=0; it<16; ++it){
    const int c = t + 512*it;                        // 16B chunk id
    const int row = c >> 5, col8 = (c & 31) << 3;
    u32x4 v = *(const u32x4*)(lsc + ((size_t)c << 3));
    *(u32x4*)(&Cout[(size_t)(m0 + row)*N + n0 + col8]) = v;
  }
  #undef BAR
  #undef SETP1
  #undef SETP0
}

// ---------------- 128x128 MFMA GEMM (kept for small GEMMs) -----------------
// OUT_KIND: 1 = f32 out, 2 = f32 out + residual
template<int OUT_KIND>
__global__ __launch_bounds__(256) void gemm_bt(
    const u16* __restrict__ A, const u16* __restrict__ Bt,
    const float* __restrict__ bias, const float* __restrict__ res,
    void* __restrict__ Cout, int M, int N, int K, int nbx)
{
  __shared__ u16 sA[128*32];
  __shared__ u16 sB[128*32];
  const int nwg = gridDim.x;
  const int q8 = nwg >> 3;
  const int bid = blockIdx.x;
  const int swz = (bid & 7) * q8 + (bid >> 3);
  const int bx = swz % nbx, by = swz / nbx;
  const int m0 = by * 128, n0 = bx * 128;
  const int t = threadIdx.x;
  const int w = t >> 6, lane = t & 63;
  const int wr = w >> 1, wc = w & 1;

  f32x4 acc[4][4];
  #pragma unroll
  for (int mi=0;mi<4;mi++)
    #pragma unroll
    for (int ni=0;ni<4;ni++)
      acc[mi][ni] = (f32x4){0.f,0.f,0.f,0.f};

  const int rST = w*32 + (lane>>2);
  const int cSRC = (((lane&3) ^ ((lane>>3)&3))) * 8;
  const u16* gA = A + (size_t)(m0 + rST)*K + cSRC;
  const u16* gB = Bt + (size_t)(n0 + rST)*K + cSRC;
  u16* lA = sA + (w*32)*32;
  u16* lB = sB + (w*32)*32;
  const int kc = lane >> 4;
  const int koff = (kc ^ (((lane&15)>>1)&3)) * 8;

  for (int k0 = 0; k0 < K; k0 += 32) {
    __syncthreads();
    __builtin_amdgcn_global_load_lds(GLOBAL_AS(gA),                LDS_AS(lA),          16, 0, 0);
    __builtin_amdgcn_global_load_lds(GLOBAL_AS(gA + 16*(size_t)K), LDS_AS(lA + 16*32),  16, 0, 0);
    __builtin_amdgcn_global_load_lds(GLOBAL_AS(gB),                LDS_AS(lB),          16, 0, 0);
    __builtin_amdgcn_global_load_lds(GLOBAL_AS(gB + 16*(size_t)K), LDS_AS(lB + 16*32),  16, 0, 0);
    gA += 32; gB += 32;
    __syncthreads();

    short8 af[4], bfr[4];
    #pragma unroll
    for (int mi=0;mi<4;mi++)
      af[mi] = *(const short8*)&sA[(wr*64 + mi*16 + (lane&15))*32 + koff];
    #pragma unroll
    for (int ni=0;ni<4;ni++)
      bfr[ni] = *(const short8*)&sB[(wc*64 + ni*16 + (lane&15))*32 + koff];
    #pragma unroll
    for (int mi=0;mi<4;mi++)
      #pragma unroll
      for (int ni=0;ni<4;ni++)
        acc[mi][ni] = __builtin_amdgcn_mfma_f32_16x16x32_bf16(af[mi], bfr[ni], acc[mi][ni], 0, 0, 0);
  }

  #pragma unroll
  for (int ni=0;ni<4;ni++){
    const int col = n0 + wc*64 + ni*16 + (lane&15);
    const float bc = bias[col];
    #pragma unroll
    for (int mi=0;mi<4;mi++){
      const int row0 = m0 + wr*64 + mi*16 + (lane>>4)*4;
      #pragma unroll
      for (int r=0;r<4;r++){
        float v = acc[mi][ni][r] + bc;
        size_t off = (size_t)(row0+r)*N + col;
        if constexpr (OUT_KIND == 1) ((float*)Cout)[off] = v;
        else                         ((float*)Cout)[off] = v + res[off];
      }
    }
  }
}

// ---------------- deformable sampling + attention-weighted accumulate ------
#define NQ_ 4096
#define LV_ 21504

__global__ __launch_bounds__(192) void sample_kernel(
    const float* __restrict__ offattn, const float* __restrict__ refp,
    const u16* __restrict__ value, u16* __restrict__ accb)
{
  __shared__ float s_w[2][4][72];
  __shared__ int   s_idx[2][4][72];
  __shared__ float s_at[2][72];
  const int t = threadIdx.x;

  if (t < 144) {
    const int qi = t / 72, s = t % 72;
    const int bq = blockIdx.x*2 + qi;
    const float* row = offattn + (size_t)bq * 256;
    const int j = s % 12, l = j >> 2;
    const float Wf = (l==0) ? 128.f : ((l==1) ? 64.f : 32.f);
    const int   Wi = (l==0) ? 128   : ((l==1) ? 64   : 32);
    const int   st = (l==0) ? 0     : ((l==1) ? 16384 : 20480);
    const float rx = refp[((size_t)bq*3 + l)*2 + 0];
    const float ry = refp[((size_t)bq*3 + l)*2 + 1];
    const float px = rx*Wf + row[2*s]   - 0.5f;
    const float py = ry*Wf + row[2*s+1] - 0.5f;
    const float x0f = floorf(px), y0f = floorf(py);
    const int x0 = (int)x0f, y0 = (int)y0f;
    const float fx = px - x0f, fy = py - y0f;
    #pragma unroll
    for (int c=0;c<4;c++){
      const int dx = c & 1, dy = c >> 1;
      const int ix = x0 + dx, iy = y0 + dy;
      const float wgt = (dx ? fx : 1.f-fx) * (dy ? fy : 1.f-fy);
      const bool ok = (ix >= 0) && (ix < Wi) && (iy >= 0) && (iy < Wi);
      const int cx = min(max(ix,0),Wi-1), cy = min(max(iy,0),Wi-1);
      s_w[qi][c][s]   = ok ? wgt : 0.f;
      s_idx[qi][c][s] = st + cy*Wi + cx;
    }
  } else if (t < 156) {
    const int u = t - 144, qi = u / 6, h = u % 6;
    const int bq = blockIdx.x*2 + qi;
    const float* lg = offattn + (size_t)bq * 256 + 144 + h*12;
    float m = lg[0];
    #pragma unroll
    for (int j2=1;j2<12;j2++) m = fmaxf(m, lg[j2]);
    float e[12]; float sum = 0.f;
    #pragma unroll
    for (int j2=0;j2<12;j2++){ e[j2] = __expf(lg[j2]-m); sum += e[j2]; }
    const float inv = 1.f/sum;
    #pragma unroll
    for (int j2=0;j2<12;j2++) s_at[qi][h*12+j2] = e[j2]*inv;
  }
  __syncthreads();

  const int qi = t / 96, tt = t % 96;
  const int bq = blockIdx.x*2 + qi;
  const int b = bq >> 12;
  const int cb = tt * 8;
  const int h = cb >> 7;
  const u16* vb = value + (size_t)b * LV_ * 768;

  float ax[8];
  #pragma unroll
  for (int k=0;k<8;k++) ax[k] = 0.f;

  #pragma unroll 2
  for (int j2=0;j2<12;j2++){
    const int s = h*12 + j2;
    const float at = s_at[qi][s];
    float sx[8];
    #pragma unroll
    for (int k=0;k<8;k++) sx[k] = 0.f;
    #pragma unroll
    for (int c=0;c<4;c++){
      const float wgt = s_w[qi][c][s];
      const u32x4 u = *(const u32x4*)(vb + (size_t)s_idx[qi][c][s]*768 + cb);
      sx[0] += wgt * lo16(u[0]); sx[1] += wgt * hi16(u[0]);
      sx[2] += wgt * lo16(u[1]); sx[3] += wgt * hi16(u[1]);
      sx[4] += wgt * lo16(u[2]); sx[5] += wgt * hi16(u[2]);
      sx[6] += wgt * lo16(u[3]); sx[7] += wgt * hi16(u[3]);
    }
    #pragma unroll
    for (int k=0;k<8;k++) ax[k] += at * sx[k];
  }

  u16* ob = accb + (size_t)bq * 768 + cb;
  u32x4 o;
  #pragma unroll
  for (int k=0;k<4;k++)
    o[k] = ((uint32_t)f2bf(ax[2*k+1]) << 16) | (uint32_t)f2bf(ax[2*k]);
  *(u32x4*)ob = o;
}

// ---------------------------------------------------------------------------
extern "C" void kernel_launch(void* const* d_in, const int* in_sizes, int n_in,
                              void* d_out, int out_size, void* d_ws, size_t ws_size,
                              hipStream_t stream) {
  (void)in_sizes; (void)n_in; (void)out_size; (void)ws_size;
  const float* query = (const float*)d_in[0];
  const float* refp  = (const float*)d_in[1];
  const float* feat  = (const float*)d_in[2];
  const float* qn_g  = (const float*)d_in[3];
  const float* qn_b  = (const float*)d_in[4];
  const float* fn_g  = (const float*)d_in[5];
  const float* fn_b  = (const float*)d_in[6];
  const float* Wv    = (const float*)d_in[7];
  const float* bv    = (const float*)d_in[8];
  const float* Ws    = (const float*)d_in[9];
  const float* bs    = (const float*)d_in[10];
  const float* Wa    = (const float*)d_in[11];
  const float* ba    = (const float*)d_in[12];
  const float* Wo    = (const float*)d_in[13];
  const float* bo    = (const float*)d_in[14];
  float* out = (float*)d_out;

  constexpr size_t SZ_FLN  = (size_t)43008*768*2;
  constexpr size_t SZ_QLN  = (size_t)8192*768*2;
  constexpr size_t SZ_W    = (size_t)768*768*2;
  constexpr size_t SZ_WSAT = (size_t)256*768*2;
  char* ws = (char*)d_ws;
  u16*  fln   = (u16*)(ws);
  u16*  value = (u16*)(ws + SZ_FLN);
  u16*  qln   = (u16*)(ws + 2*SZ_FLN);
  u16*  Wvt   = (u16*)(ws + 2*SZ_FLN + SZ_QLN);
  u16*  Wot   = (u16*)(ws + 2*SZ_FLN + SZ_QLN + SZ_W);
  u16*  Wsat  = (u16*)(ws + 2*SZ_FLN + SZ_QLN + 2*SZ_W);
  float* bsa  = (float*)(ws + 2*SZ_FLN + SZ_QLN + 2*SZ_W + SZ_WSAT);
  float* offattn = (float*)fln;
  u16*   accb    = qln;

  // 1) LayerNorms -> bf16
  ln_cast<<<8192, 256, 0, stream>>>(query, qn_g, qn_b, qln);
  ln_cast<<<43008, 256, 0, stream>>>(feat, fn_g, fn_b, fln);

  // 2) weight pre-transpose/cast
  tcast<<<dim3(24,24), 256, 0, stream>>>(Wv, 768, 768, Wvt);
  tcast<<<dim3(24,24), 256, 0, stream>>>(Wo, 768, 768, Wot);
  hipMemsetAsync(Wsat, 0, SZ_WSAT, stream);
  tcast<<<dim3(5,24), 256, 0, stream>>>(Ws, 144, 144, Wsat);
  tcast<<<dim3(3,24), 256, 0, stream>>>(Wa, 72, 72, Wsat + (size_t)144*768);
  pack_bsa<<<1, 256, 0, stream>>>(bs, ba, bsa);

  // 3) value = LN(feat) @ Wv + bv -> bf16 [43008, 768]   (168x3 = 504 blocks)
  gemm8<<<504, 512, 0, stream>>>(fln, Wvt, bv, value, 43008, 768, 768, 3);

  // 4) off/attn logits = LN(query) @ [Ws|Wa] -> f32 [8192, 256]
  gemm_bt<1><<<128, 256, 0, stream>>>(qln, Wsat, bsa, nullptr, offattn, 8192, 256, 768, 2);

  // 5) deformable sampling -> bf16 [8192, 768]
  sample_kernel<<<4096, 192, 0, stream>>>(offattn, refp, value, accb);

  // 6) out = acc @ Wo + bo + query -> f32
  gemm_bt<2><<<384, 256, 0, stream>>>(accb, Wot, bo, query, out, 8192, 768, 768, 6);
}

// Round 8
// 210.455 us; speedup vs baseline: 1.1052x; 1.1052x over previous
//
#include <hip/hip_runtime.h>
#include <cstdint>
#include <cstddef>

typedef unsigned short u16;
typedef __attribute__((ext_vector_type(8))) short short8;
typedef __attribute__((ext_vector_type(4))) float f32x4;
typedef __attribute__((ext_vector_type(4))) unsigned int u32x4;

#define GLOBAL_AS(p) ((const __attribute__((address_space(1))) void*)(p))
#define LDS_AS(p)    ((__attribute__((address_space(3))) void*)(p))
typedef __attribute__((address_space(3))) const void* lds_cp;

__device__ __forceinline__ float bf2f(u16 u){
  union { uint32_t u; float f; } c; c.u = ((uint32_t)u) << 16; return c.f;
}
__device__ __forceinline__ float lo16(uint32_t u){
  union { uint32_t u; float f; } c; c.u = u << 16; return c.f;
}
__device__ __forceinline__ float hi16(uint32_t u){
  union { uint32_t u; float f; } c; c.u = u & 0xffff0000u; return c.f;
}
__device__ __forceinline__ u16 f2bf(float f){
  union { float f; uint32_t u; } c; c.f = f;
  uint32_t r = c.u + 0x7fffu + ((c.u >> 16) & 1u);
  return (u16)(r >> 16);
}

// ---------------- LayerNorm + cast to bf16 (one block per 768-elem row) ----
__global__ __launch_bounds__(256) void ln_cast(const float* __restrict__ x,
    const float* __restrict__ g, const float* __restrict__ bta,
    u16* __restrict__ y)
{
  const size_t row = blockIdx.x;
  const float* xr = x + row * 768;
  const int t = threadIdx.x;
  float v0 = xr[t], v1 = xr[t+256], v2 = xr[t+512];
  float s = v0+v1+v2;
  float q = v0*v0 + v1*v1 + v2*v2;
  #pragma unroll
  for (int o=1;o<64;o<<=1){ s += __shfl_xor(s,o); q += __shfl_xor(q,o); }
  __shared__ float rs_[4], rq_[4];
  if ((t & 63) == 0){ rs_[t>>6] = s; rq_[t>>6] = q; }
  __syncthreads();
  s = rs_[0]+rs_[1]+rs_[2]+rs_[3];
  q = rq_[0]+rq_[1]+rq_[2]+rq_[3];
  const float m = s * (1.f/768.f);
  const float var = q * (1.f/768.f) - m*m;
  const float rstd = rsqrtf(var + 1e-6f);
  u16* yr = y + row * 768;
  yr[t]     = f2bf((v0-m)*rstd*g[t]     + bta[t]);
  yr[t+256] = f2bf((v1-m)*rstd*g[t+256] + bta[t+256]);
  yr[t+512] = f2bf((v2-m)*rstd*g[t+512] + bta[t+512]);
}

// ---------------- transpose+cast: out[n][k] = bf16(in[k*ld + n]), k<768 ----
__global__ __launch_bounds__(256) void tcast(const float* __restrict__ in,
    int ld, int ncnt, u16* __restrict__ out)
{
  __shared__ float tile[32][33];
  const int tx = threadIdx.x & 31, ty = threadIdx.x >> 5;
  const int n0 = blockIdx.x * 32, k0 = blockIdx.y * 32;
  #pragma unroll
  for (int i=0;i<4;i++){
    int k = k0 + ty + 8*i, n = n0 + tx;
    tile[ty+8*i][tx] = (n < ncnt) ? in[(size_t)k*ld + n] : 0.f;
  }
  __syncthreads();
  #pragma unroll
  for (int i=0;i<4;i++){
    int n = n0 + ty + 8*i, k = k0 + tx;
    if (n < ncnt) out[(size_t)n*768 + k] = f2bf(tile[tx][ty+8*i]);
  }
}

__global__ void pack_bsa(const float* __restrict__ bs, const float* __restrict__ ba,
                         float* __restrict__ bsa)
{
  int t = threadIdx.x;
  bsa[t] = (t < 144) ? bs[t] : ((t < 216) ? ba[t-144] : 0.f);
}

// ============ 128x128 pipelined MFMA GEMM, 2 blocks/CU (v4) ================
// 256 thr = 4 waves (2M x 2N), per-wave C = 64x64 (acc 64 VGPR). BK=64.
// LDS = 2 dbuf x (A 128x64 + B 128x64) bf16 = 64 KiB -> 2 independent
// blocks/CU (launch_bounds(256,2)): one block's barrier/vmcnt stalls are
// filled by the co-resident block's MFMAs (m114 mechanism) -- this is what
// the 1-block/CU 256^2 versions (R3-R6, all ~680 TF) lacked.
// Iter = 2 K-tiles (a=2i buf0, b=2i+1 buf1), 4 phases (jp = M-half):
//   phase: {4 A ds_reads (+8 B at tile start) | 2 half-tile stages} -> bar
//          -> lgkmcnt(0)+sched_barrier -> setprio(1) 16 MFMA setprio(0)
//          -> [vmcnt(4) @p1,p3] -> bar
// Stage ledger (region-liveness verified; 2 loads/thread per half-tile):
//   p0: buf1.A(h0,h1) <- tile b   (buf1.A dead since p3(i-1))
//   p1: buf0.B(h0,h1) <- tile a+2 (buf0.B dead after p0)   VM4
//   p2: buf0.A(h0,h1) <- tile a+2 (buf0.A dead after p1)
//   p3: buf1.B(h0,h1) <- tile b+3 (buf1.B dead after p2)   VM4
// VM4 @p1: in-flight = p1's 4 loads -> tile b (B@p3(i-1), A@p0) landed.
// VM4 @p3: in-flight = p3's 4 loads -> tile a+2 (B@p1, A@p2) landed.
// Tail: stage kt clamped to NT-1 (dead regions). vmcnt never 0 in loop.
// OUT: 0 = bf16 out via LDS restage; 1 = f32 out; 2 = f32 + residual.
template<int OUT>
__global__ __launch_bounds__(256, 2) void gemm128p(
    const u16* __restrict__ A, const u16* __restrict__ Bt,
    const float* __restrict__ bias, const float* __restrict__ res,
    void* __restrict__ Cout, int M, int N, int K, int nbx)
{
  __shared__ u16 lds[2][2][128*64];
  const int nwg = gridDim.x;                       // multiple of 8
  const int bid = blockIdx.x;
  const int swz = (bid & 7) * (nwg >> 3) + (bid >> 3);
  const int bx = swz % nbx, by = swz / nbx;
  const int m0 = by*128, n0 = bx*128;
  const int t = threadIdx.x, w = t >> 6, lane = t & 63;
  const int wr = w >> 1, wc = w & 1;
  const int NT = K >> 6;
  const int lr = lane & 15;

  // staging: half-tile (64 rows x 64 cols) = 2 gload_lds(16B)/thread.
  // chunk ch = q*256+t -> row ch>>3, chunk-slot ch&7; source col-chunk
  // pre-swizzled (LDS write is lane-linear): c_src = (t&7) ^ ((t>>3)&7).
  const int stColU = (((t & 7) ^ ((t >> 3) & 7)) << 3);

  f32x4 acc[4][4];
  #pragma unroll
  for (int mi=0;mi<4;mi++)
    #pragma unroll
    for (int ni=0;ni<4;ni++)
      acc[mi][ni] = (f32x4){0.f,0.f,0.f,0.f};

  #define STG(op, half, kt, buf, G, gbase)                                     \
    { const u16* g_ = (G) + (size_t)((gbase) + (half)*64 + (t>>3))*K           \
                          + (kt)*64 + stColU;                                  \
      u16* l_ = &lds[buf][op][(half)*64*64 + (w<<9)];                          \
      __builtin_amdgcn_global_load_lds(GLOBAL_AS(g_), LDS_AS(l_), 16,0,0);     \
      __builtin_amdgcn_global_load_lds(GLOBAL_AS(g_ + (size_t)32*K),           \
                                       LDS_AS(l_ + 2048), 16,0,0); }

  // read-side swizzle: chunk c at row R lives in slot c ^ (R&7); R&7 = lane&7
  const int slot0 = (((lane>>4)    ) ^ (lane&7)) * 8;   // kk=0
  const int slot1 = (((lane>>4) + 4) ^ (lane&7)) * 8;   // kk=1

  // prologue: tile0 (B,A) -> buf0; tile1 B -> buf1. vmcnt(4): tile0 landed.
  STG(1,0,0,0, Bt, n0); STG(1,1,0,0, Bt, n0);
  STG(0,0,0,0, A,  m0); STG(0,1,0,0, A,  m0);
  STG(1,0,1,1, Bt, n0); STG(1,1,1,1, Bt, n0);
  asm volatile("s_waitcnt vmcnt(4)" ::: "memory");
  __builtin_amdgcn_s_barrier();

  const u16* lA0 = &lds[0][0][(wr*64 + lr)*64];
  const u16* lB0 = &lds[0][1][(wc*64 + lr)*64];
  const u16* lA1 = &lds[1][0][(wr*64 + lr)*64];
  const u16* lB1 = &lds[1][1][(wc*64 + lr)*64];

  short8 bf_[4][2], aR[4];

  #define DSR(dst_, p_)                                                        \
    asm volatile("ds_read_b128 %0, %1" : "=v"(dst_) : "v"((lds_cp)(p_)))

  #define READ_A4(lA_, jp_)                                                    \
    DSR(aR[0], (lA_) + ((jp_)*32     )*64 + slot0);                            \
    DSR(aR[1], (lA_) + ((jp_)*32     )*64 + slot1);                            \
    DSR(aR[2], (lA_) + ((jp_)*32 + 16)*64 + slot0);                            \
    DSR(aR[3], (lA_) + ((jp_)*32 + 16)*64 + slot1);

  #define READ_B8(lB_)                                                         \
    DSR(bf_[0][0], (lB_) +  0*64 + slot0);  DSR(bf_[0][1], (lB_) +  0*64 + slot1); \
    DSR(bf_[1][0], (lB_) + 16*64 + slot0);  DSR(bf_[1][1], (lB_) + 16*64 + slot1); \
    DSR(bf_[2][0], (lB_) + 32*64 + slot0);  DSR(bf_[2][1], (lB_) + 32*64 + slot1); \
    DSR(bf_[3][0], (lB_) + 48*64 + slot0);  DSR(bf_[3][1], (lB_) + 48*64 + slot1);

  #define MFMA16(jp_)                                                          \
    _Pragma("unroll")                                                          \
    for (int ni=0; ni<4; ++ni) {                                               \
      acc[2*(jp_)  ][ni] = __builtin_amdgcn_mfma_f32_16x16x32_bf16(aR[0], bf_[ni][0], acc[2*(jp_)  ][ni], 0,0,0); \
      acc[2*(jp_)  ][ni] = __builtin_amdgcn_mfma_f32_16x16x32_bf16(aR[1], bf_[ni][1], acc[2*(jp_)  ][ni], 0,0,0); \
      acc[2*(jp_)+1][ni] = __builtin_amdgcn_mfma_f32_16x16x32_bf16(aR[2], bf_[ni][0], acc[2*(jp_)+1][ni], 0,0,0); \
      acc[2*(jp_)+1][ni] = __builtin_amdgcn_mfma_f32_16x16x32_bf16(aR[3], bf_[ni][1], acc[2*(jp_)+1][ni], 0,0,0); \
    }

  #define LGKM0 do { asm volatile("s_waitcnt lgkmcnt(0)" ::: "memory");        \
                     __builtin_amdgcn_sched_barrier(0); } while(0)
  #define BAR   __builtin_amdgcn_s_barrier()
  #define VM4   asm volatile("s_waitcnt vmcnt(4)" ::: "memory")
  #define SETP1 __builtin_amdgcn_s_setprio(1)
  #define SETP0 __builtin_amdgcn_s_setprio(0)

  const int NITER = NT >> 1;
  for (int i = 0; i < NITER; ++i) {
    const int bt = 2*i + 1;
    const int a2 = (2*i+2 < NT) ? 2*i+2 : NT-1;
    const int b2 = (2*i+3 < NT) ? 2*i+3 : NT-1;

    // p0: tile a (buf0), jp0
    READ_B8(lB0); READ_A4(lA0, 0);
    STG(0,0,bt,1, A, m0); STG(0,1,bt,1, A, m0);     // buf1.A <- tile b
    BAR; LGKM0;
    SETP1; MFMA16(0); SETP0;
    BAR;

    // p1: tile a, jp1
    READ_A4(lA0, 1);
    STG(1,0,a2,0, Bt, n0); STG(1,1,a2,0, Bt, n0);   // buf0.B <- a+2
    BAR; LGKM0;
    SETP1; MFMA16(1); SETP0;
    VM4; BAR;                                       // tile b landed

    // p2: tile b (buf1), jp0
    READ_B8(lB1); READ_A4(lA1, 0);
    STG(0,0,a2,0, A, m0); STG(0,1,a2,0, A, m0);     // buf0.A <- a+2
    BAR; LGKM0;
    SETP1; MFMA16(0); SETP0;
    BAR;

    // p3: tile b, jp1
    READ_A4(lA1, 1);
    STG(1,0,b2,1, Bt, n0); STG(1,1,b2,1, Bt, n0);   // buf1.B <- b+3
    BAR; LGKM0;
    SETP1; MFMA16(1); SETP0;
    VM4; BAR;                                       // tile a+2 landed
  }
  #undef STG
  #undef READ_A4
  #undef READ_B8
  #undef MFMA16
  #undef DSR
  #undef VM4

  // ---- epilogue: restage C through LDS for coalesced stores ----
  asm volatile("s_waitcnt vmcnt(0)" ::: "memory");   // drain tail stages
  BAR;                                               // LDS dead -> reuse
  if constexpr (OUT == 0) {
    u16* lsc = (u16*)lds;                            // 128x128 u16 = 32 KiB
    #pragma unroll
    for (int ni=0;ni<4;ni++){
      const int col = wc*64 + ni*16 + lr;
      const float bc = bias[n0 + col];
      #pragma unroll
      for (int mi=0;mi<4;mi++){
        const int row0 = wr*64 + mi*16 + (lane>>4)*4;
        #pragma unroll
        for (int r=0;r<4;r++)
          lsc[(row0+r)*128 + col] = f2bf(acc[mi][ni][r] + bc);
      }
    }
    asm volatile("s_waitcnt lgkmcnt(0)" ::: "memory");
    BAR;
    u16* C = (u16*)Cout;
    #pragma unroll
    for (int it=0; it<8; ++it){
      const int c = t + 256*it;                      // 16B chunk id
      const int row = c >> 4, col8 = (c & 15) << 3;
      u32x4 v = *(const u32x4*)(lsc + ((size_t)c << 3));
      *(u32x4*)(&C[(size_t)(m0 + row)*N + n0 + col8]) = v;
    }
  } else {
    float* lsf = (float*)lds;                        // 128x128 f32 = 64 KiB
    #pragma unroll
    for (int ni=0;ni<4;ni++){
      const int col = wc*64 + ni*16 + lr;
      const float bc = bias[n0 + col];
      #pragma unroll
      for (int mi=0;mi<4;mi++){
        const int row0 = wr*64 + mi*16 + (lane>>4)*4;
        #pragma unroll
        for (int r=0;r<4;r++)
          lsf[(row0+r)*128 + col] = acc[mi][ni][r] + bc;
      }
    }
    asm volatile("s_waitcnt lgkmcnt(0)" ::: "memory");
    BAR;
    float* C = (float*)Cout;
    #pragma unroll
    for (int it=0; it<16; ++it){
      const int c = t + 256*it;                      // 16B chunk id (4 f32)
      const int row = c >> 5, col4 = (c & 31) << 2;
      f32x4 v = *(const f32x4*)(lsf + ((size_t)c << 2));
      if constexpr (OUT == 2) {
        const f32x4 rv = *(const f32x4*)(&res[(size_t)(m0 + row)*N + n0 + col4]);
        v = v + rv;
      }
      *(f32x4*)(&C[(size_t)(m0 + row)*N + n0 + col4]) = v;
    }
  }
  #undef BAR
  #undef LGKM0
  #undef SETP1
  #undef SETP0
}

// ---------------- deformable sampling + attention-weighted accumulate ------
#define NQ_ 4096
#define LV_ 21504

__global__ __launch_bounds__(192) void sample_kernel(
    const float* __restrict__ offattn, const float* __restrict__ refp,
    const u16* __restrict__ value, u16* __restrict__ accb)
{
  __shared__ float s_w[2][4][72];
  __shared__ int   s_idx[2][4][72];
  __shared__ float s_at[2][72];
  const int t = threadIdx.x;

  if (t < 144) {
    const int qi = t / 72, s = t % 72;
    const int bq = blockIdx.x*2 + qi;
    const float* row = offattn + (size_t)bq * 256;
    const int j = s % 12, l = j >> 2;
    const float Wf = (l==0) ? 128.f : ((l==1) ? 64.f : 32.f);
    const int   Wi = (l==0) ? 128   : ((l==1) ? 64   : 32);
    const int   st = (l==0) ? 0     : ((l==1) ? 16384 : 20480);
    const float rx = refp[((size_t)bq*3 + l)*2 + 0];
    const float ry = refp[((size_t)bq*3 + l)*2 + 1];
    const float px = rx*Wf + row[2*s]   - 0.5f;
    const float py = ry*Wf + row[2*s+1] - 0.5f;
    const float x0f = floorf(px), y0f = floorf(py);
    const int x0 = (int)x0f, y0 = (int)y0f;
    const float fx = px - x0f, fy = py - y0f;
    #pragma unroll
    for (int c=0;c<4;c++){
      const int dx = c & 1, dy = c >> 1;
      const int ix = x0 + dx, iy = y0 + dy;
      const float wgt = (dx ? fx : 1.f-fx) * (dy ? fy : 1.f-fy);
      const bool ok = (ix >= 0) && (ix < Wi) && (iy >= 0) && (iy < Wi);
      const int cx = min(max(ix,0),Wi-1), cy = min(max(iy,0),Wi-1);
      s_w[qi][c][s]   = ok ? wgt : 0.f;
      s_idx[qi][c][s] = st + cy*Wi + cx;
    }
  } else if (t < 156) {
    const int u = t - 144, qi = u / 6, h = u % 6;
    const int bq = blockIdx.x*2 + qi;
    const float* lg = offattn + (size_t)bq * 256 + 144 + h*12;
    float m = lg[0];
    #pragma unroll
    for (int j2=1;j2<12;j2++) m = fmaxf(m, lg[j2]);
    float e[12]; float sum = 0.f;
    #pragma unroll
    for (int j2=0;j2<12;j2++){ e[j2] = __expf(lg[j2]-m); sum += e[j2]; }
    const float inv = 1.f/sum;
    #pragma unroll
    for (int j2=0;j2<12;j2++) s_at[qi][h*12+j2] = e[j2]*inv;
  }
  __syncthreads();

  const int qi = t / 96, tt = t % 96;
  const int bq = blockIdx.x*2 + qi;
  const int b = bq >> 12;
  const int cb = tt * 8;
  const int h = cb >> 7;
  const u16* vb = value + (size_t)b * LV_ * 768;

  float ax[8];
  #pragma unroll
  for (int k=0;k<8;k++) ax[k] = 0.f;

  #pragma unroll 2
  for (int j2=0;j2<12;j2++){
    const int s = h*12 + j2;
    const float at = s_at[qi][s];
    float sx[8];
    #pragma unroll
    for (int k=0;k<8;k++) sx[k] = 0.f;
    #pragma unroll
    for (int c=0;c<4;c++){
      const float wgt = s_w[qi][c][s];
      const u32x4 u = *(const u32x4*)(vb + (size_t)s_idx[qi][c][s]*768 + cb);
      sx[0] += wgt * lo16(u[0]); sx[1] += wgt * hi16(u[0]);
      sx[2] += wgt * lo16(u[1]); sx[3] += wgt * hi16(u[1]);
      sx[4] += wgt * lo16(u[2]); sx[5] += wgt * hi16(u[2]);
      sx[6] += wgt * lo16(u[3]); sx[7] += wgt * hi16(u[3]);
    }
    #pragma unroll
    for (int k=0;k<8;k++) ax[k] += at * sx[k];
  }

  u16* ob = accb + (size_t)bq * 768 + cb;
  u32x4 o;
  #pragma unroll
  for (int k=0;k<4;k++)
    o[k] = ((uint32_t)f2bf(ax[2*k+1]) << 16) | (uint32_t)f2bf(ax[2*k]);
  *(u32x4*)ob = o;
}

// ---------------------------------------------------------------------------
extern "C" void kernel_launch(void* const* d_in, const int* in_sizes, int n_in,
                              void* d_out, int out_size, void* d_ws, size_t ws_size,
                              hipStream_t stream) {
  (void)in_sizes; (void)n_in; (void)out_size; (void)ws_size;
  const float* query = (const float*)d_in[0];
  const float* refp  = (const float*)d_in[1];
  const float* feat  = (const float*)d_in[2];
  const float* qn_g  = (const float*)d_in[3];
  const float* qn_b  = (const float*)d_in[4];
  const float* fn_g  = (const float*)d_in[5];
  const float* fn_b  = (const float*)d_in[6];
  const float* Wv    = (const float*)d_in[7];
  const float* bv    = (const float*)d_in[8];
  const float* Ws    = (const float*)d_in[9];
  const float* bs    = (const float*)d_in[10];
  const float* Wa    = (const float*)d_in[11];
  const float* ba    = (const float*)d_in[12];
  const float* Wo    = (const float*)d_in[13];
  const float* bo    = (const float*)d_in[14];
  float* out = (float*)d_out;

  constexpr size_t SZ_FLN  = (size_t)43008*768*2;
  constexpr size_t SZ_QLN  = (size_t)8192*768*2;
  constexpr size_t SZ_W    = (size_t)768*768*2;
  constexpr size_t SZ_WSAT = (size_t)256*768*2;
  char* ws = (char*)d_ws;
  u16*  fln   = (u16*)(ws);
  u16*  value = (u16*)(ws + SZ_FLN);
  u16*  qln   = (u16*)(ws + 2*SZ_FLN);
  u16*  Wvt   = (u16*)(ws + 2*SZ_FLN + SZ_QLN);
  u16*  Wot   = (u16*)(ws + 2*SZ_FLN + SZ_QLN + SZ_W);
  u16*  Wsat  = (u16*)(ws + 2*SZ_FLN + SZ_QLN + 2*SZ_W);
  float* bsa  = (float*)(ws + 2*SZ_FLN + SZ_QLN + 2*SZ_W + SZ_WSAT);
  float* offattn = (float*)fln;
  u16*   accb    = qln;

  // 1) LayerNorms -> bf16
  ln_cast<<<8192, 256, 0, stream>>>(query, qn_g, qn_b, qln);
  ln_cast<<<43008, 256, 0, stream>>>(feat, fn_g, fn_b, fln);

  // 2) weight pre-transpose/cast
  tcast<<<dim3(24,24), 256, 0, stream>>>(Wv, 768, 768, Wvt);
  tcast<<<dim3(24,24), 256, 0, stream>>>(Wo, 768, 768, Wot);
  hipMemsetAsync(Wsat, 0, SZ_WSAT, stream);
  tcast<<<dim3(5,24), 256, 0, stream>>>(Ws, 144, 144, Wsat);
  tcast<<<dim3(3,24), 256, 0, stream>>>(Wa, 72, 72, Wsat + (size_t)144*768);
  pack_bsa<<<1, 256, 0, stream>>>(bs, ba, bsa);

  // 3) value = LN(feat) @ Wv + bv -> bf16 [43008, 768]  (336x6 = 2016 blocks)
  gemm128p<0><<<2016, 256, 0, stream>>>(fln, Wvt, bv, nullptr, value, 43008, 768, 768, 6);

  // 4) off/attn logits = LN(query) @ [Ws|Wa] -> f32 [8192, 256]  (64x2)
  gemm128p<1><<<128, 256, 0, stream>>>(qln, Wsat, bsa, nullptr, offattn, 8192, 256, 768, 2);

  // 5) deformable sampling -> bf16 [8192, 768]
  sample_kernel<<<4096, 192, 0, stream>>>(offattn, refp, value, accb);

  // 6) out = acc @ Wo + bo + query -> f32  (64x6 = 384 blocks)
  gemm128p<2><<<384, 256, 0, stream>>>(accb, Wot, bo, query, out, 8192, 768, 768, 6);
}